// Round 1
// 1119.452 us; speedup vs baseline: 1.4636x; 1.4636x over previous
//
#include <hip/hip_runtime.h>
#include <cmath>

#define HID 51
#define BATCH 256
#define BLK 512      // 8 waves

typedef _Float16 half2_t __attribute__((ext_vector_type(2)));

// One block per batch element (grid = 256 = #CUs).
// Single barrier per tick. Recurrence h_l(t-1)->gates_l(t)->h_l(t) is kept
// INTRA-WAVE: lane u of a "heavy" wave owns unit u of its layer (4 gates,
// 4x26 fdot2 vs Whh rows held in 104 packed-fp16 VGPRs), does the cell
// update, writes h to LDS, broadcast-reads it back (7x ds_read_b128, same
// addr = broadcast), and computes next tick's Whh dots into registers
// (never touches LDS). Only the feed-forward Wih partials cross waves,
// double-buffered by tick parity with a 1-tick skew.
//
// Waves (wave%4 = SIMD):  0: L0 heavy (t=tau)    1: L1 heavy (t=tau-2)
//   2: L2 heavy (t=tau-4)                        3: I1a Wih(l1) gates i,f
//   4: I1b Wih(l1) g,o    5: I2a Wih(l2) i,f     6: I2b Wih(l2) g,o
//   7: O: out = Wl.h2(tau-5)+bl -> obuf ring, coalesced 64-wide flush
// I-waves at tick tau consume h written at tau-1 (slot (tau-1)&1) and write
// gPA slot tau&1; heavy waves at tau consume gPA slot (tau-1)&1. Race-free
// with one barrier. waves_per_eu(2,2) -> 256 arch VGPRs so w2[104] stays
// resident (default occupancy target would cap at 128 and spill).

__device__ __forceinline__ float fsig(float v) {
    return __builtin_amdgcn_rcpf(1.f + __expf(-v));
}
__device__ __forceinline__ float ftanh(float v) {
    const float e = __expf(2.f * v);                 // inf-safe
    return fmaf(-2.f, __builtin_amdgcn_rcpf(e + 1.f), 1.f);
}

__attribute__((amdgpu_waves_per_eu(2, 2)))
__global__ __launch_bounds__(BLK)
void lstm3_kernel(const float* __restrict__ x,
                  const float* __restrict__ Wih1, const float* __restrict__ Whh1,
                  const float* __restrict__ bih1, const float* __restrict__ bhh1,
                  const float* __restrict__ Wih,  const float* __restrict__ Whh,
                  const float* __restrict__ bih,  const float* __restrict__ bhh,
                  const float* __restrict__ Wl,   const float* __restrict__ bl,
                  float* __restrict__ out, int T)
{
    const int b    = blockIdx.x;
    const int tid  = threadIdx.x;
    const int wave = tid >> 6;
    const int lane = tid & 63;
    const int u    = lane;
    const int uu   = (u < HID) ? u : (HID - 1);   // clamp for safe global loads

    __shared__ __align__(16) float  xbuf[2048];
    __shared__ __align__(16) int    hrow[3][2][32];   // h as fp16, 128B rows, dbuf
    __shared__ __align__(16) float4 gPA[2][2][64];    // Wih partials (i,f,g,o), dbuf
    __shared__ __align__(16) float  obuf[128];        // output ring (2 x 64)

    for (int i = tid; i < T; i += BLK) xbuf[i] = x[(size_t)b * T + i];
    if (tid < 192) ((int*)hrow)[tid] = 0;             // h(-1) = 0 (both parities)
    for (int i = tid; i < 1024; i += BLK) ((float*)gPA)[i] = 0.f;

    // ---------------- per-role weight staging (one-time) ----------------
    half2_t w2[104];
    #pragma unroll
    for (int j = 0; j < 104; ++j) w2[j] = half2_t{(_Float16)0.f, (_Float16)0.f};
    float bias4[4] = {0.f, 0.f, 0.f, 0.f};
    float wx4[4]   = {0.f, 0.f, 0.f, 0.f};
    float outb     = 0.f;

    if (wave < 3) {                                   // heavy: Whh rows, 4 gates of unit u
        const int l = wave;
        const float* Wbase = (l == 0) ? Whh1 : (Whh + (size_t)(l - 1) * 204 * HID);
        #pragma unroll
        for (int k = 0; k < 4; ++k) {
            const int g = k * HID + uu;
            const float* rp = Wbase + (size_t)g * HID;
            #pragma unroll
            for (int j = 0; j < 25; ++j)
                w2[k * 26 + j] = half2_t{(_Float16)rp[2 * j], (_Float16)rp[2 * j + 1]};
            w2[k * 26 + 25] = half2_t{(_Float16)rp[50], (_Float16)0.f};
            if (l == 0) { bias4[k] = bih1[g] + bhh1[g]; wx4[k] = Wih1[g]; }
            else        { const int gg = (l - 1) * 204 + g; bias4[k] = bih[gg] + bhh[gg]; }
        }
    } else if (wave < 7) {                            // I-waves: Wih rows, 2 gates of unit u
        const int iw   = wave - 3;
        const int srcl = iw >> 1;                     // 0: feeds L1, 1: feeds L2
        const int sub  = iw & 1;                      // 0: gates (i,f)  1: (g,o)
        #pragma unroll
        for (int k = 0; k < 2; ++k) {
            const int g = (sub * 2 + k) * HID + uu;
            const float* rp = Wih + ((size_t)srcl * 204 + g) * HID;
            #pragma unroll
            for (int j = 0; j < 25; ++j)
                w2[k * 26 + j] = half2_t{(_Float16)rp[2 * j], (_Float16)rp[2 * j + 1]};
            w2[k * 26 + 25] = half2_t{(_Float16)rp[50], (_Float16)0.f};
        }
    } else {                                          // O-wave: Wl row
        #pragma unroll
        for (int j = 0; j < 25; ++j)
            w2[j] = half2_t{(_Float16)Wl[2 * j], (_Float16)Wl[2 * j + 1]};
        w2[25] = half2_t{(_Float16)Wl[50], (_Float16)0.f};
        outb = bl[0];
    }

    float c_state = 0.f;
    float wacc[4] = {0.f, 0.f, 0.f, 0.f};             // Whh . h(t) carried across ticks

    if (wave < 3) __builtin_amdgcn_s_setprio(1);      // heavy waves win SIMD arbitration

    __syncthreads();

    const int TICKS = T + 5;
    for (int tau = 0; tau < TICKS; ++tau) {
        if (wave < 3) {
            // ---------------- heavy: combine + cell + h + Whh dots ----------------
            const int l  = wave;
            const int tc = tau - 2 * l;               // wave-uniform
            if ((unsigned)tc < (unsigned)T) {
                float gi, gf, gg_, go;
                if (l == 0) {
                    const float xv = xbuf[tc];        // uniform-addr broadcast read
                    gi  = fmaf(wx4[0], xv, bias4[0]) + wacc[0];
                    gf  = fmaf(wx4[1], xv, bias4[1]) + wacc[1];
                    gg_ = fmaf(wx4[2], xv, bias4[2]) + wacc[2];
                    go  = fmaf(wx4[3], xv, bias4[3]) + wacc[3];
                } else {
                    const float4 q = gPA[l - 1][(tau - 1) & 1][u];
                    gi  = bias4[0] + wacc[0] + q.x;
                    gf  = bias4[1] + wacc[1] + q.y;
                    gg_ = bias4[2] + wacc[2] + q.z;
                    go  = bias4[3] + wacc[3] + q.w;
                }
                const float c = fmaf(fsig(gf), c_state, fsig(gi) * ftanh(gg_));
                c_state = c;
                const float h = fsig(go) * ftanh(c);
                if (u < HID)
                    ((_Float16*)&hrow[l][tau & 1][0])[u] = (_Float16)h;  // pads stay 0
            }
            const int tn = tc + 1;                    // Whh dots for NEXT time step
            if ((unsigned)tn < (unsigned)T) {
                int4 hv[7];
                const int4* hp = (const int4*)&hrow[l][tau & 1][0];      // own, broadcast
                #pragma unroll
                for (int k = 0; k < 7; ++k) hv[k] = hp[k];
                const half2_t* hh = (const half2_t*)hv;
                float a0 = 0.f, a1 = 0.f, a2 = 0.f, a3 = 0.f;
                #pragma unroll
                for (int j = 0; j < 26; ++j) {
                    a0 = __builtin_amdgcn_fdot2(w2[j],      hh[j], a0, false);
                    a1 = __builtin_amdgcn_fdot2(w2[26 + j], hh[j], a1, false);
                    a2 = __builtin_amdgcn_fdot2(w2[52 + j], hh[j], a2, false);
                    a3 = __builtin_amdgcn_fdot2(w2[78 + j], hh[j], a3, false);
                }
                wacc[0] = a0; wacc[1] = a1; wacc[2] = a2; wacc[3] = a3;
            }
        } else if (wave < 7) {
            // ---------------- I-waves: Wih partials (1-tick skew) ----------------
            const int iw   = wave - 3;
            const int srcl = iw >> 1;
            const int sub  = iw & 1;
            const int ti   = tau - 1 - 2 * srcl;
            if ((unsigned)ti < (unsigned)T) {
                int4 hv[7];
                const int4* hp = (const int4*)&hrow[srcl][(tau - 1) & 1][0];
                #pragma unroll
                for (int k = 0; k < 7; ++k) hv[k] = hp[k];
                const half2_t* hh = (const half2_t*)hv;
                float a0 = 0.f, a1 = 0.f;
                #pragma unroll
                for (int j = 0; j < 26; ++j) {
                    a0 = __builtin_amdgcn_fdot2(w2[j],      hh[j], a0, false);
                    a1 = __builtin_amdgcn_fdot2(w2[26 + j], hh[j], a1, false);
                }
                if (u < HID)
                    ((float2*)&gPA[srcl][tau & 1][u])[sub] = make_float2(a0, a1);
            }
        } else {
            // ---------------- O-wave: output dot + coalesced flush ----------------
            const int to = tau - 5;
            if ((unsigned)to < (unsigned)T) {
                int4 hv[7];
                const int4* hp = (const int4*)&hrow[2][(tau - 1) & 1][0];
                #pragma unroll
                for (int k = 0; k < 7; ++k) hv[k] = hp[k];
                const half2_t* hh = (const half2_t*)hv;
                float a0 = outb, a1 = 0.f;
                #pragma unroll
                for (int j = 0; j < 26; ++j) {
                    if (j & 1) a1 = __builtin_amdgcn_fdot2(w2[j], hh[j], a1, false);
                    else       a0 = __builtin_amdgcn_fdot2(w2[j], hh[j], a0, false);
                }
                if (lane == 0) obuf[to & 127] = a0 + a1;
            }
            if ((tau & 63) == 4 && tau >= 68) {       // block [tau-68, tau-5] complete
                const int t0 = tau - 68;
                out[(size_t)b * T + t0 + lane] = obuf[(t0 & 64) + lane];
            }
        }
        __syncthreads();                              // the ONLY barrier per tick
    }
}

extern "C" void kernel_launch(void* const* d_in, const int* in_sizes, int n_in,
                              void* d_out, int out_size, void* d_ws, size_t ws_size,
                              hipStream_t stream) {
    const float* x    = (const float*)d_in[0];
    const float* Wih1 = (const float*)d_in[1];
    const float* Whh1 = (const float*)d_in[2];
    const float* bih1 = (const float*)d_in[3];
    const float* bhh1 = (const float*)d_in[4];
    const float* Wih  = (const float*)d_in[5];
    const float* Whh  = (const float*)d_in[6];
    const float* bih  = (const float*)d_in[7];
    const float* bhh  = (const float*)d_in[8];
    const float* Wl   = (const float*)d_in[9];
    const float* bl   = (const float*)d_in[10];
    float* out = (float*)d_out;

    const int T = in_sizes[0] / BATCH;   // 2048 (flush assumes T % 64 == 0)
    lstm3_kernel<<<BATCH, BLK, 0, stream>>>(x, Wih1, Whh1, bih1, bhh1,
                                            Wih, Whh, bih, bhh, Wl, bl, out, T);
}